// Round 1
// baseline (8992.607 us; speedup 1.0000x reference)
//
#include <hip/hip_runtime.h>
#include <stdint.h>

// Problem constants
#define B_  64
#define S_  2048
#define V_  50257
#define E_  300
#define EP  320      // E padded to multiple of 32 (zero-filled)
#define H_  256
#define G4  1024     // 4*H

typedef short bf16x8 __attribute__((ext_vector_type(8)));
typedef float f32x4  __attribute__((ext_vector_type(4)));
typedef _Float16 half2_t __attribute__((ext_vector_type(2)));

#if defined(__has_builtin)
#  if __has_builtin(__builtin_amdgcn_fdot2)
#    define USE_FDOT2 1
#  endif
#endif
#ifndef USE_FDOT2
#  define USE_FDOT2 0
#endif

__device__ __forceinline__ unsigned short f2bf_rne(float x){
    unsigned u = __builtin_bit_cast(unsigned, x);
    u += 0x7fffu + ((u >> 16) & 1u);
    return (unsigned short)(u >> 16);
}
__device__ __forceinline__ float bf2f(unsigned short h){
    unsigned u = ((unsigned)h) << 16;
    return __builtin_bit_cast(float, u);
}
__device__ __forceinline__ float sigm_(float x){
    return __builtin_amdgcn_rcpf(1.f + __expf(-x));
}
__device__ __forceinline__ float tanh_(float x){
    return 1.f - 2.f * __builtin_amdgcn_rcpf(1.f + __expf(2.f * x));
}
__device__ __forceinline__ void dot_acc(unsigned wu, half2_t hv, float& a){
#if USE_FDOT2
    a = __builtin_amdgcn_fdot2(__builtin_bit_cast(half2_t, wu), hv, a, false);
#else
    half2_t wv = __builtin_bit_cast(half2_t, wu);
    a += (float)wv[0] * (float)hv[0] + (float)wv[1] * (float)hv[1];
#endif
}

// ---------------- prep kernels ----------------

__global__ void prep_emb(const float* __restrict__ emb, unsigned short* __restrict__ out, int total){
    for(int i = blockIdx.x * blockDim.x + threadIdx.x; i < total; i += gridDim.x * blockDim.x){
        int r = i / EP, c = i % EP;
        float v = (c < E_) ? emb[(size_t)r * E_ + c] : 0.f;
        out[i] = f2bf_rne(v);
    }
}

__global__ void prep_wxt(const float* __restrict__ Wx, unsigned short* __restrict__ out){
    int i = blockIdx.x * blockDim.x + threadIdx.x;   // over G4*EP
    if(i >= G4 * EP) return;
    int j = i / EP, k = i % EP;
    float v = (k < E_) ? Wx[(size_t)k * G4 + j] : 0.f;
    out[i] = f2bf_rne(v);
}

// Pack Wh (fp32 [256][1024]) into per-thread fp16-pair layout for the LSTM kernel.
// LSTM thread tid (0..511): cg=tid>>2 (cols j=cg*8+m, m=0..7), kg=tid&3 (kp = kg*32+kpl).
// kpl in [0,20)  -> reg-resident:  wreg[(kpl*8+m)*512 + tid]
// kpl in [20,32) -> streamed:      wstr[((kpl-20)*8+m)*512 + tid]
__global__ void prep_wh(const float* __restrict__ Wh, unsigned* __restrict__ wreg, unsigned* __restrict__ wstr){
    int i = blockIdx.x * blockDim.x + threadIdx.x;   // over 512*256
    if(i >= 512 * 256) return;
    int tid = i & 511, s = i >> 9;
    int cg = tid >> 2, kg = tid & 3;
    int kpl = s >> 3, m = s & 7;
    int j  = cg * 8 + m;
    int kp = kg * 32 + kpl;
    float w0 = Wh[(size_t)(2 * kp)     * G4 + j];
    float w1 = Wh[(size_t)(2 * kp + 1) * G4 + j];
    union { unsigned u; _Float16 h[2]; } p;
    p.h[0] = (_Float16)w0; p.h[1] = (_Float16)w1;
    if(kpl < 20) wreg[(size_t)(kpl * 8 + m) * 512 + tid] = p.u;
    else         wstr[(size_t)((kpl - 20) * 8 + m) * 512 + tid] = p.u;
}

// ---------------- X = embed @ Wx + b  (bf16 MFMA, no-LDS direct-fragment GEMM) ----------------
// Grid: (B * (W/64)) M-chunks x 8 N-blocks. Block = 256 thr = 4 waves (2x2 wave grid).
// Writes X (bf16) indexed [b*W + (t-t0)][1024], bias folded in.
__global__ __launch_bounds__(256) void gemm_x(
    const unsigned short* __restrict__ embB, const unsigned short* __restrict__ wxtB,
    const int* __restrict__ tok, const int* __restrict__ lens, const float* __restrict__ bias,
    unsigned short* __restrict__ X, int t0, int W)
{
    int mchunks = W >> 6;
    int bid = blockIdx.x;
    int nb  = bid & 7;
    int mb  = bid >> 3;
    int b   = mb / mchunks;
    int tc  = mb % mchunks;
    int tbase = t0 + tc * 64;
    if(tbase >= lens[b]) return;

    int tid = threadIdx.x, l = tid & 63, w = tid >> 6;
    int wm = (w & 1) * 32, wn = (w >> 1) * 64;
    int lr = l & 15, kq = l >> 4;          // fragment row/col lane, k-quarter
    int n0 = nb * 128 + wn;

    int tok0 = tok[(size_t)b * S_ + tbase + wm + lr];
    int tok1 = tok[(size_t)b * S_ + tbase + wm + 16 + lr];
    const unsigned short* a0 = embB + (size_t)tok0 * EP + 8 * kq;
    const unsigned short* a1 = embB + (size_t)tok1 * EP + 8 * kq;

    f32x4 acc[2][4] = {};
    #pragma unroll
    for(int k0 = 0; k0 < EP; k0 += 32){
        bf16x8 af0 = *(const bf16x8*)(a0 + k0);
        bf16x8 af1 = *(const bf16x8*)(a1 + k0);
        #pragma unroll
        for(int nf = 0; nf < 4; nf++){
            bf16x8 bfr = *(const bf16x8*)(wxtB + (size_t)(n0 + nf * 16 + lr) * EP + k0 + 8 * kq);
            acc[0][nf] = __builtin_amdgcn_mfma_f32_16x16x32_bf16(af0, bfr, acc[0][nf], 0, 0, 0);
            acc[1][nf] = __builtin_amdgcn_mfma_f32_16x16x32_bf16(af1, bfr, acc[1][nf], 0, 0, 0);
        }
    }
    // C layout: col = n0+nf*16+(l&15), row = 4*(l>>4)+v  (m89-verified mapping)
    int twbase = tc * 64 + wm;
    #pragma unroll
    for(int mf = 0; mf < 2; mf++){
        #pragma unroll
        for(int nf = 0; nf < 4; nf++){
            int col = n0 + nf * 16 + lr;
            float bv = bias[col];
            #pragma unroll
            for(int v = 0; v < 4; v++){
                int tw = twbase + mf * 16 + 4 * kq + v;
                X[((size_t)b * W + tw) * G4 + col] = f2bf_rne(acc[mf][nf][v] + bv);
            }
        }
    }
}

// ---------------- LSTM recurrence: 1 block per batch, 512 threads ----------------
// Thread tid: cg=tid>>2 owns 8 z-columns j=cg*8+m; kg=tid&3 owns k-pairs kp in [kg*32, kg*32+32).
// 160 weight pairs resident in VGPRs, 96 streamed from L2 each step.
// h kept fp32 in regs (per unit-thread), broadcast as fp16 pairs via 4 bank-staggered LDS copies.

#define DOTREG(K0,K1) \
  { _Pragma("unroll") for(int kpl=(K0); kpl<(K1); kpl++){ \
      unsigned hpair = *(const unsigned*)&h16[kg][2*(kg*32+kpl)]; \
      half2_t hv = __builtin_bit_cast(half2_t, hpair); \
      _Pragma("unroll") for(int m=0;m<8;m++) dot_acc(wr[kpl*8+m], hv, acc[m]); } }

#define DOTSTR(BUF,K0) \
  { _Pragma("unroll") for(int kk=0; kk<3; kk++){ \
      unsigned hpair = *(const unsigned*)&h16[kg][2*(kg*32+(K0)+kk)]; \
      half2_t hv = __builtin_bit_cast(half2_t, hpair); \
      _Pragma("unroll") for(int m=0;m<8;m++) dot_acc(BUF[kk*8+m], hv, acc[m]); } }

#define LOADC(BUF,S0) \
  { _Pragma("unroll") for(int s=0;s<24;s++) BUF[s] = wstr_g[(size_t)((S0)+s)*512 + tid]; }

__global__ __launch_bounds__(512, 2) void lstm_step(
    const unsigned* __restrict__ wreg_g, const unsigned* __restrict__ wstr_g,
    const unsigned short* __restrict__ X, const int* __restrict__ lens,
    float* __restrict__ cst, float* __restrict__ hst, float* __restrict__ hfin,
    int t0, int t1, int W)
{
    __shared__ float zs[G4];
    __shared__ _Float16 h16[4][258];   // 4 bank-staggered copies of h (256 fp16) + 2-elem pad

    int b   = blockIdx.x;
    int tid = threadIdx.x;
    int cg  = tid >> 2, kg = tid & 3;
    int len = lens[b];
    int te  = min(t1, len);

    // resident weights
    unsigned wr[160];
    #pragma unroll
    for(int s = 0; s < 160; s++) wr[s] = wreg_g[(size_t)s * 512 + tid];

    float c_u = 0.f, h_u = 0.f;
    if(tid < H_){
        if(t0 != 0){ c_u = cst[b * H_ + tid]; h_u = hst[b * H_ + tid]; }
        #pragma unroll
        for(int cp = 0; cp < 4; cp++) h16[cp][tid] = (_Float16)h_u;
    }

    for(int t = t0; t < te; t++){
        __syncthreads();          // h16 ready (init or previous update); zs WAR

        float acc[8] = {0.f,0.f,0.f,0.f,0.f,0.f,0.f,0.f};
        unsigned c0[24], c1[24], c2[24], c3[24];

        LOADC(c0, 0);  DOTREG(0, 5);
        LOADC(c1, 24); DOTREG(5, 10);
        DOTSTR(c0, 20);
        LOADC(c2, 48); DOTREG(10, 15);
        DOTSTR(c1, 23);
        LOADC(c3, 72); DOTREG(15, 20);
        DOTSTR(c2, 26);
        DOTSTR(c3, 29);

        // reduce partials across kg (lanes xor 1,2 within quad)
        #pragma unroll
        for(int m = 0; m < 8; m++){
            float a = acc[m];
            a += __shfl_xor(a, 1);
            a += __shfl_xor(a, 2);
            acc[m] = a;
        }
        if(kg == 0){
            #pragma unroll
            for(int m = 0; m < 8; m++) zs[cg * 8 + m] = acc[m];
        }
        __syncthreads();          // zs ready

        if(tid < H_){
            size_t xb = ((size_t)b * W + (t - t0)) * G4 + tid;
            float zi = zs[tid]          + bf2f(X[xb]);
            float zf = zs[H_ + tid]     + bf2f(X[xb + 256]);
            float zg = zs[2 * H_ + tid] + bf2f(X[xb + 512]);
            float zo = zs[3 * H_ + tid] + bf2f(X[xb + 768]);
            float fi = sigm_(zi), ff = sigm_(zf), gg = tanh_(zg), fo = sigm_(zo);
            c_u = ff * c_u + fi * gg;
            h_u = fo * tanh_(c_u);
            if(t == len - 1) hfin[b * H_ + tid] = h_u;
            #pragma unroll
            for(int cp = 0; cp < 4; cp++) h16[cp][tid] = (_Float16)h_u;
        }
    }

    if(tid < H_){ cst[b * H_ + tid] = c_u; hst[b * H_ + tid] = h_u; }
}

// ---------------- head: out[b] = tanh(hfin[b]@W1 + b1) @ W2 ----------------
__global__ void head_k(const float* __restrict__ hfin, const float* __restrict__ W1,
                       const float* __restrict__ b1, const float* __restrict__ W2,
                       float* __restrict__ out)
{
    int b = blockIdx.x, u = threadIdx.x;    // 256 threads
    float a = b1[u];
    #pragma unroll 4
    for(int k = 0; k < H_; k++) a += hfin[b * H_ + k] * W1[k * H_ + u];
    float v = tanh_(a) * W2[u];
    #pragma unroll
    for(int o = 32; o; o >>= 1) v += __shfl_down(v, o);
    __shared__ float red[4];
    if((u & 63) == 0) red[u >> 6] = v;
    __syncthreads();
    if(u == 0) out[b] = red[0] + red[1] + red[2] + red[3];
}

// ---------------- launch ----------------
extern "C" void kernel_launch(void* const* d_in, const int* in_sizes, int n_in,
                              void* d_out, int out_size, void* d_ws, size_t ws_size,
                              hipStream_t stream)
{
    (void)in_sizes; (void)n_in; (void)out_size;
    const int*   inputs  = (const int*)  d_in[0];
    const int*   lengths = (const int*)  d_in[1];
    const float* emb     = (const float*)d_in[2];
    const float* Wx      = (const float*)d_in[3];
    const float* Wh      = (const float*)d_in[4];
    const float* bias    = (const float*)d_in[5];
    const float* W1      = (const float*)d_in[6];
    const float* b1      = (const float*)d_in[7];
    const float* W2      = (const float*)d_in[8];
    float* out = (float*)d_out;

    char* ws = (char*)d_ws;
    size_t off = 0;
    auto alloc = [&](size_t bytes){ size_t o = off; off = (off + bytes + 255) & ~(size_t)255; return o; };
    size_t o_emb  = alloc((size_t)V_ * EP * 2);
    size_t o_wxt  = alloc((size_t)G4 * EP * 2);
    size_t o_wreg = alloc((size_t)160 * 512 * 4);
    size_t o_wstr = alloc((size_t)96 * 512 * 4);
    size_t o_cst  = alloc((size_t)B_ * H_ * 4);
    size_t o_hst  = alloc((size_t)B_ * H_ * 4);
    size_t o_hfin = alloc((size_t)B_ * H_ * 4);
    size_t fixed  = off;

    int W = 2048;                       // X time-window (shrink if workspace small)
    while(W > 64 && fixed + (size_t)B_ * W * G4 * 2 + 256 > ws_size) W >>= 1;
    size_t o_X = alloc((size_t)B_ * W * G4 * 2);

    unsigned short* embB = (unsigned short*)(ws + o_emb);
    unsigned short* wxtB = (unsigned short*)(ws + o_wxt);
    unsigned* wregB = (unsigned*)(ws + o_wreg);
    unsigned* wstrB = (unsigned*)(ws + o_wstr);
    float* cstB  = (float*)(ws + o_cst);
    float* hstB  = (float*)(ws + o_hst);
    float* hfinB = (float*)(ws + o_hfin);
    unsigned short* Xb = (unsigned short*)(ws + o_X);

    prep_emb<<<2048, 256, 0, stream>>>(emb, embB, V_ * EP);
    prep_wxt<<<(G4 * EP + 255) / 256, 256, 0, stream>>>(Wx, wxtB);
    prep_wh<<<(512 * 256 + 255) / 256, 256, 0, stream>>>(Wh, wregB, wstrB);

    for(int t0 = 0; t0 < S_; t0 += W){
        gemm_x<<<B_ * (W / 64) * 8, 256, 0, stream>>>(embB, wxtB, inputs, lengths, bias, Xb, t0, W);
        lstm_step<<<B_, 512, 0, stream>>>(wregB, wstrB, Xb, lengths, cstB, hstB, hfinB, t0, t0 + W, W);
    }
    head_k<<<B_, 256, 0, stream>>>(hfinB, W1, b1, W2, out);
}

// Round 5
// 6148.338 us; speedup vs baseline: 1.4626x; 1.4626x over previous
//
#include <hip/hip_runtime.h>
#include <stdint.h>

// Problem constants
#define B_  64
#define S_  2048
#define V_  50257
#define E_  300
#define EP  320      // E padded to multiple of 32 (zero-filled)
#define H_  256
#define G4  1024     // 4*H

typedef short bf16x8 __attribute__((ext_vector_type(8)));
typedef float f32x4  __attribute__((ext_vector_type(4)));
typedef _Float16 half2_t __attribute__((ext_vector_type(2)));

#if defined(__has_builtin)
#  if __has_builtin(__builtin_amdgcn_fdot2)
#    define USE_FDOT2 1
#  endif
#endif
#ifndef USE_FDOT2
#  define USE_FDOT2 0
#endif

__device__ __forceinline__ unsigned short f2bf_rne(float x){
    unsigned u = __builtin_bit_cast(unsigned, x);
    u += 0x7fffu + ((u >> 16) & 1u);
    return (unsigned short)(u >> 16);
}
__device__ __forceinline__ float bf2f(unsigned short h){
    unsigned u = ((unsigned)h) << 16;
    return __builtin_bit_cast(float, u);
}
__device__ __forceinline__ float sigm_(float x){
    return __builtin_amdgcn_rcpf(1.f + __expf(-x));
}
__device__ __forceinline__ float tanh_(float x){
    return 1.f - 2.f * __builtin_amdgcn_rcpf(1.f + __expf(2.f * x));
}
__device__ __forceinline__ void dot_acc(unsigned wu, half2_t hv, float& a){
#if USE_FDOT2
    a = __builtin_amdgcn_fdot2(__builtin_bit_cast(half2_t, wu), hv, a, false);
#else
    half2_t wv = __builtin_bit_cast(half2_t, wu);
    a += (float)wv[0] * (float)hv[0] + (float)wv[1] * (float)hv[1];
#endif
}

// ---------------- prep kernels ----------------

__global__ void prep_emb(const float* __restrict__ emb, unsigned short* __restrict__ out, int total){
    for(int i = blockIdx.x * blockDim.x + threadIdx.x; i < total; i += gridDim.x * blockDim.x){
        int r = i / EP, c = i % EP;
        float v = (c < E_) ? emb[(size_t)r * E_ + c] : 0.f;
        out[i] = f2bf_rne(v);
    }
}

__global__ void prep_wxt(const float* __restrict__ Wx, unsigned short* __restrict__ out){
    int i = blockIdx.x * blockDim.x + threadIdx.x;   // over G4*EP
    if(i >= G4 * EP) return;
    int j = i / EP, k = i % EP;
    float v = (k < E_) ? Wx[(size_t)k * G4 + j] : 0.f;
    out[i] = f2bf_rne(v);
}

// Pack Wh (fp32 [256][1024]) into per-thread fp16-pair layout (EXACT R1 mapping,
// split point moved 20 -> 24).
// LSTM thread tid (0..511): cg=tid>>2 owns cols j=cg*8+m (m=0..7); kg=tid&3 owns
// k-pairs kp = kg*32 + kpl, kpl in [0,32).
// kpl in [0,24)  -> resident:  wreg[(kpl*8+m)*512 + tid]
// kpl in [24,32) -> streamed:  wstr[((kpl-24)*8+m)*512 + tid]
__global__ void prep_wh(const float* __restrict__ Wh, unsigned* __restrict__ wreg, unsigned* __restrict__ wstr){
    int i = blockIdx.x * blockDim.x + threadIdx.x;   // over 512*256
    if(i >= 512 * 256) return;
    int tid = i & 511, s = i >> 9;
    int cg = tid >> 2, kg = tid & 3;
    int kpl = s >> 3, m = s & 7;
    int j  = cg * 8 + m;
    int kp = kg * 32 + kpl;
    float w0 = Wh[(size_t)(2 * kp)     * G4 + j];
    float w1 = Wh[(size_t)(2 * kp + 1) * G4 + j];
    union { unsigned u; _Float16 h[2]; } p;
    p.h[0] = (_Float16)w0; p.h[1] = (_Float16)w1;
    if(kpl < 24) wreg[(size_t)(kpl * 8 + m) * 512 + tid] = p.u;
    else         wstr[(size_t)((kpl - 24) * 8 + m) * 512 + tid] = p.u;
}

// ---------------- X = embed @ Wx + b  (bf16 MFMA, no-LDS direct-fragment GEMM) ----------------
__global__ __launch_bounds__(256) void gemm_x(
    const unsigned short* __restrict__ embB, const unsigned short* __restrict__ wxtB,
    const int* __restrict__ tok, const int* __restrict__ lens, const float* __restrict__ bias,
    unsigned short* __restrict__ X, int t0, int W)
{
    int mchunks = W >> 6;
    int bid = blockIdx.x;
    int nb  = bid & 7;
    int mb  = bid >> 3;
    int b   = mb / mchunks;
    int tc  = mb % mchunks;
    int tbase = t0 + tc * 64;
    if(tbase >= lens[b]) return;

    int tid = threadIdx.x, l = tid & 63, w = tid >> 6;
    int wm = (w & 1) * 32, wn = (w >> 1) * 64;
    int lr = l & 15, kq = l >> 4;
    int n0 = nb * 128 + wn;

    int tok0 = tok[(size_t)b * S_ + tbase + wm + lr];
    int tok1 = tok[(size_t)b * S_ + tbase + wm + 16 + lr];
    const unsigned short* a0 = embB + (size_t)tok0 * EP + 8 * kq;
    const unsigned short* a1 = embB + (size_t)tok1 * EP + 8 * kq;

    f32x4 acc[2][4] = {};
    #pragma unroll
    for(int k0 = 0; k0 < EP; k0 += 32){
        bf16x8 af0 = *(const bf16x8*)(a0 + k0);
        bf16x8 af1 = *(const bf16x8*)(a1 + k0);
        #pragma unroll
        for(int nf = 0; nf < 4; nf++){
            bf16x8 bfr = *(const bf16x8*)(wxtB + (size_t)(n0 + nf * 16 + lr) * EP + k0 + 8 * kq);
            acc[0][nf] = __builtin_amdgcn_mfma_f32_16x16x32_bf16(af0, bfr, acc[0][nf], 0, 0, 0);
            acc[1][nf] = __builtin_amdgcn_mfma_f32_16x16x32_bf16(af1, bfr, acc[1][nf], 0, 0, 0);
        }
    }
    int twbase = tc * 64 + wm;
    #pragma unroll
    for(int mf = 0; mf < 2; mf++){
        #pragma unroll
        for(int nf = 0; nf < 4; nf++){
            int col = n0 + nf * 16 + lr;
            float bv = bias[col];
            #pragma unroll
            for(int v = 0; v < 4; v++){
                int tw = twbase + mf * 16 + 4 * kq + v;
                X[((size_t)b * W + tw) * G4 + col] = f2bf_rne(acc[mf][nf][v] + bv);
            }
        }
    }
}

// ---------------- LSTM recurrence: 1 block per batch, 512 threads (R1 structure) ----------------
// __launch_bounds__(512, 1): min 1 BLOCK/CU (CUDA semantics) -> 256-VGPR cap.
// 192 weight pairs VGPR-resident; 64 streamed from L2 in two 32-reg batches,
// each issued ~1 half-dot-phase (~390 cyc) before first use. X row prefetched
// at loop top into registers (consumed in epilogue after the barrier).
__global__ __launch_bounds__(512, 1) void lstm_step(
    const unsigned* __restrict__ wreg_g, const unsigned* __restrict__ wstr_g,
    const unsigned short* __restrict__ X, const int* __restrict__ lens,
    float* __restrict__ cst, float* __restrict__ hst, float* __restrict__ hfin,
    int t0, int t1, int W)
{
    __shared__ float zs[G4];
    __shared__ _Float16 h16[4][258];   // 4 bank-staggered copies of h + pad (R1-proven)

    int b   = blockIdx.x;
    int tid = threadIdx.x;
    int cg  = tid >> 2, kg = tid & 3;
    int len = lens[b];
    int te  = min(t1, len);

    // resident weights: 192 regs
    unsigned wr[192];
    #pragma unroll
    for(int s = 0; s < 192; s++) wr[s] = wreg_g[(size_t)s * 512 + tid];

    float c_u = 0.f, h_u = 0.f;
    if(tid < H_){
        if(t0 != 0){ c_u = cst[b * H_ + tid]; h_u = hst[b * H_ + tid]; }
        #pragma unroll
        for(int cp = 0; cp < 4; cp++) h16[cp][tid] = (_Float16)h_u;
    }
    __syncthreads();    // h16 ready for first iteration

    const unsigned short* Xrow = X + ((size_t)b * W) * G4;

    for(int t = t0; t < te; t++){
        // Opaque pointer copy each iteration: prevents LICM from hoisting the
        // streamed-weight loads out of the loop (which would blow the 256-reg cap).
        const unsigned* wsp = wstr_g;
        asm volatile("" : "+v"(wsp));

        // batch 1 of streamed weights (kpl 24..27) + X prefetch — issued early
        unsigned cs1[32];
        #pragma unroll
        for(int q = 0; q < 32; q++) cs1[q] = wsp[(size_t)q * 512 + tid];

        unsigned short x0 = 0, x1 = 0, x2 = 0, x3 = 0;
        if(tid < H_){
            const unsigned short* xr = Xrow + (size_t)(t - t0) * G4;
            x0 = xr[tid]; x1 = xr[tid + 256]; x2 = xr[tid + 512]; x3 = xr[tid + 768];
        }

        float acc[8] = {0.f,0.f,0.f,0.f,0.f,0.f,0.f,0.f};

        // resident dots, first half (kpl 0..11)
        #pragma unroll
        for(int kpl = 0; kpl < 12; kpl++){
            unsigned hp = *(const unsigned*)&h16[kg][2 * (kg * 32 + kpl)];
            half2_t hv = __builtin_bit_cast(half2_t, hp);
            #pragma unroll
            for(int m = 0; m < 8; m++) dot_acc(wr[kpl * 8 + m], hv, acc[m]);
        }

        // streamed batch 1 (kpl 24..27)
        #pragma unroll
        for(int k2 = 0; k2 < 4; k2++){
            unsigned hp = *(const unsigned*)&h16[kg][2 * (kg * 32 + 24 + k2)];
            half2_t hv = __builtin_bit_cast(half2_t, hp);
            #pragma unroll
            for(int m = 0; m < 8; m++) dot_acc(cs1[k2 * 8 + m], hv, acc[m]);
        }

        // batch 2 of streamed weights (kpl 28..31) — cs1 regs are dead now
        unsigned cs2[32];
        #pragma unroll
        for(int q = 0; q < 32; q++) cs2[q] = wsp[(size_t)(32 + q) * 512 + tid];

        // resident dots, second half (kpl 12..23)
        #pragma unroll
        for(int kpl = 12; kpl < 24; kpl++){
            unsigned hp = *(const unsigned*)&h16[kg][2 * (kg * 32 + kpl)];
            half2_t hv = __builtin_bit_cast(half2_t, hp);
            #pragma unroll
            for(int m = 0; m < 8; m++) dot_acc(wr[kpl * 8 + m], hv, acc[m]);
        }

        // streamed batch 2 (kpl 28..31)
        #pragma unroll
        for(int k2 = 0; k2 < 4; k2++){
            unsigned hp = *(const unsigned*)&h16[kg][2 * (kg * 32 + 28 + k2)];
            half2_t hv = __builtin_bit_cast(half2_t, hp);
            #pragma unroll
            for(int m = 0; m < 8; m++) dot_acc(cs2[k2 * 8 + m], hv, acc[m]);
        }

        // reduce partials across kg (lanes xor 1,2 within quad)
        #pragma unroll
        for(int m = 0; m < 8; m++){
            float a = acc[m];
            a += __shfl_xor(a, 1);
            a += __shfl_xor(a, 2);
            acc[m] = a;
        }
        if(kg == 0){
            #pragma unroll
            for(int m = 0; m < 8; m++) zs[cg * 8 + m] = acc[m];
        }
        __syncthreads();          // zs ready

        if(tid < H_){
            float zi = zs[tid]          + bf2f(x0);
            float zf = zs[H_ + tid]     + bf2f(x1);
            float zg = zs[2 * H_ + tid] + bf2f(x2);
            float zo = zs[3 * H_ + tid] + bf2f(x3);
            float fi = sigm_(zi), ff = sigm_(zf), gg = tanh_(zg), fo = sigm_(zo);
            c_u = ff * c_u + fi * gg;
            h_u = fo * tanh_(c_u);
            if(t == len - 1) hfin[b * H_ + tid] = h_u;
            #pragma unroll
            for(int cp = 0; cp < 4; cp++) h16[cp][tid] = (_Float16)h_u;
        }
        __syncthreads();          // h16 ready for next iter; zs WAR
    }

    if(tid < H_){ cst[b * H_ + tid] = c_u; hst[b * H_ + tid] = h_u; }
}

// ---------------- head: out[b] = tanh(hfin[b]@W1 + b1) @ W2 ----------------
__global__ void head_k(const float* __restrict__ hfin, const float* __restrict__ W1,
                       const float* __restrict__ b1, const float* __restrict__ W2,
                       float* __restrict__ out)
{
    int b = blockIdx.x, u = threadIdx.x;    // 256 threads
    float a = b1[u];
    #pragma unroll 4
    for(int k = 0; k < H_; k++) a += hfin[b * H_ + k] * W1[k * H_ + u];
    float v = tanh_(a) * W2[u];
    #pragma unroll
    for(int o = 32; o; o >>= 1) v += __shfl_down(v, o);
    __shared__ float red[4];
    if((u & 63) == 0) red[u >> 6] = v;
    __syncthreads();
    if(u == 0) out[b] = red[0] + red[1] + red[2] + red[3];
}

// ---------------- launch ----------------
extern "C" void kernel_launch(void* const* d_in, const int* in_sizes, int n_in,
                              void* d_out, int out_size, void* d_ws, size_t ws_size,
                              hipStream_t stream)
{
    (void)in_sizes; (void)n_in; (void)out_size;
    const int*   inputs  = (const int*)  d_in[0];
    const int*   lengths = (const int*)  d_in[1];
    const float* emb     = (const float*)d_in[2];
    const float* Wx      = (const float*)d_in[3];
    const float* Wh      = (const float*)d_in[4];
    const float* bias    = (const float*)d_in[5];
    const float* W1      = (const float*)d_in[6];
    const float* b1      = (const float*)d_in[7];
    const float* W2      = (const float*)d_in[8];
    float* out = (float*)d_out;

    char* ws = (char*)d_ws;
    size_t off = 0;
    auto alloc = [&](size_t bytes){ size_t o = off; off = (off + bytes + 255) & ~(size_t)255; return o; };
    size_t o_emb  = alloc((size_t)V_ * EP * 2);
    size_t o_wxt  = alloc((size_t)G4 * EP * 2);
    size_t o_wreg = alloc((size_t)192 * 512 * 4);
    size_t o_wstr = alloc((size_t)64 * 512 * 4);
    size_t o_cst  = alloc((size_t)B_ * H_ * 4);
    size_t o_hst  = alloc((size_t)B_ * H_ * 4);
    size_t o_hfin = alloc((size_t)B_ * H_ * 4);
    size_t fixed  = off;

    int W = 2048;                       // X time-window (shrink if workspace small)
    while(W > 64 && fixed + (size_t)B_ * W * G4 * 2 + 256 > ws_size) W >>= 1;
    size_t o_X = alloc((size_t)B_ * W * G4 * 2);

    unsigned short* embB = (unsigned short*)(ws + o_emb);
    unsigned short* wxtB = (unsigned short*)(ws + o_wxt);
    unsigned* wregB = (unsigned*)(ws + o_wreg);
    unsigned* wstrB = (unsigned*)(ws + o_wstr);
    float* cstB  = (float*)(ws + o_cst);
    float* hstB  = (float*)(ws + o_hst);
    float* hfinB = (float*)(ws + o_hfin);
    unsigned short* Xb = (unsigned short*)(ws + o_X);

    prep_emb<<<2048, 256, 0, stream>>>(emb, embB, V_ * EP);
    prep_wxt<<<(G4 * EP + 255) / 256, 256, 0, stream>>>(Wx, wxtB);
    prep_wh<<<512, 256, 0, stream>>>(Wh, wregB, wstrB);

    for(int t0 = 0; t0 < S_; t0 += W){
        gemm_x<<<B_ * (W / 64) * 8, 256, 0, stream>>>(embB, wxtB, inputs, lengths, bias, Xb, t0, W);
        lstm_step<<<B_, 512, 0, stream>>>(wregB, wstrB, Xb, lengths, cstB, hstB, hfinB, t0, t0 + W, W);
    }
    head_k<<<B_, 256, 0, stream>>>(hfinB, W1, b1, W2, out);
}